// Round 9
// baseline (148.214 us; speedup 1.0000x reference)
//
#include <hip/hip_runtime.h>
#include <math.h>

#define BB 64
#define WW 128
#define FF 64
#define HH 4
#define OW 128

// ---------------------------------------------------------------------------
// Kernel 1: projections (r6 kernel verbatim — model-exact 20.5 us at 16
// waves/CU). LDS-resident GEMM, K split in two 64-wide phases, 33.4 KB ->
// 4 blocks/CU. Grid 1024 = b(64) x rt(16). 4x4 register tile.
// Output: fs/fd [B][H][node i][d].
// ---------------------------------------------------------------------------
__global__ __launch_bounds__(256) void gat_proj(
    const float* __restrict__ x,     // [B][128 k][64 f]
    const float* __restrict__ Wsrc,  // [512][128]
    const float* __restrict__ bsrc,
    const float* __restrict__ Wdst,
    const float* __restrict__ bdst,
    float* __restrict__ fs,          // [B][H][64][128]
    float* __restrict__ fd)
{
    __shared__ float xl[64 * FF];        // 16 KB [k_half][f]
    __shared__ float wl[64 * 68];        // 17 KB [r][k_half], pad 68
    __shared__ float bl[64];

    const int b  = blockIdx.x >> 4;
    const int rt = blockIdx.x & 15;
    const bool is_src = rt < 8;
    const int rm0 = (rt & 7) * 64;

    const float* Wm = is_src ? Wsrc : Wdst;
    const float* bm = is_src ? bsrc : bdst;

    const int t  = threadIdx.x;
    const int f0 = (t & 15) * 4;
    const int r0 = (t >> 4) * 4;

    float acc[4][4] = {};

    for (int kp = 0; kp < 2; ++kp) {
        {
            const float4* xs = (const float4*)(x + (size_t)b * (WW * FF) + kp * 64 * FF);
            float4* xd = (float4*)xl;
            #pragma unroll
            for (int p = 0; p < 4; ++p)
                xd[p * 256 + t] = xs[p * 256 + t];
            float4* wd = (float4*)wl;
            #pragma unroll
            for (int p = 0; p < 4; ++p) {
                int idx = p * 256 + t;
                int r = idx >> 4, kq = idx & 15;
                wd[r * 17 + kq] =
                    *(const float4*)(Wm + (size_t)(rm0 + r) * WW + kp * 64 + kq * 4);
            }
            if (kp == 0 && t < 64) bl[t] = bm[rm0 + t];
        }
        __syncthreads();

        #pragma unroll
        for (int k0 = 0; k0 < 64; k0 += 4) {
            float4 xv[4], wv[4];
            #pragma unroll
            for (int kk = 0; kk < 4; ++kk)
                xv[kk] = *(const float4*)&xl[(k0 + kk) * FF + f0];
            #pragma unroll
            for (int rr = 0; rr < 4; ++rr)
                wv[rr] = *(const float4*)&wl[(r0 + rr) * 68 + k0];
            #pragma unroll
            for (int kk = 0; kk < 4; ++kk) {
                #pragma unroll
                for (int rr = 0; rr < 4; ++rr) {
                    const float wf = ((const float*)&wv[rr])[kk];
                    const float* xf = (const float*)&xv[kk];
                    acc[rr][0] = fmaf(xf[0], wf, acc[rr][0]);
                    acc[rr][1] = fmaf(xf[1], wf, acc[rr][1]);
                    acc[rr][2] = fmaf(xf[2], wf, acc[rr][2]);
                    acc[rr][3] = fmaf(xf[3], wf, acc[rr][3]);
                }
            }
        }
        __syncthreads();
    }

    const int h  = (rt & 7) >> 1;
    const int d0 = ((rt & 1) * 64) + r0;
    float* dst = (is_src ? fs : fd) + (((size_t)b * HH + h) * FF) * OW;
    float b0 = bl[r0 + 0], b1 = bl[r0 + 1], b2 = bl[r0 + 2], b3 = bl[r0 + 3];
    #pragma unroll
    for (int ff = 0; ff < 4; ++ff) {
        float4 o;
        o.x = acc[0][ff] + b0;
        o.y = acc[1][ff] + b1;
        o.z = acc[2][ff] + b2;
        o.w = acc[3][ff] + b3;
        *(float4*)&dst[(size_t)(f0 + ff) * OW + d0] = o;
    }
}

// ---------------------------------------------------------------------------
// Kernel 2: scores + edge-softmax + aggregation + head-mean, atomically
// accumulated straight into out. Grid 256 = (b,h), block 512 = 8 waves/CU.
// Phase 1: thread = (ie,dh,jp) owns fd[2j x 32d] IN REGISTERS; i-loop reads
//   only 8 fs-b128 per 128 VALU ops (ratio 16). Partial-d scores combined
//   via ds_add_f32 into St (pre-initialized with separable cs_i + cd_j).
// Phase 3: 4j x 4d tile, 2 b128 per 16 FMA; atomicAdd into out[b][d][j]
//   with 0.25/l folded. LDS ~92 KB -> 1 block/CU.
// ---------------------------------------------------------------------------
__global__ __launch_bounds__(512, 2) void gat_attn(
    const float* __restrict__ fs,    // [B][H][64 i][128 d]
    const float* __restrict__ fd,    // [B][H][64 j][128 d]
    const float* __restrict__ attn,  // [H][128]
    float* __restrict__ out)         // [B][128 d][64 j]  (pre-zeroed)
{
    __shared__ float fsl[FF * 132];      // 33.8 KB [i][d]
    __shared__ float fdt[OW * 68];       // 34.8 KB [d][j]
    __shared__ float St[FF * 68];        // 17.4 KB [i][j]
    __shared__ float A6[OW], B4[OW];
    __shared__ float cs[FF], cd[FF];
    __shared__ float redm[8][FF];
    __shared__ float reds[8][FF];
    __shared__ float invl[FF];

    const int h = blockIdx.x & 3;
    const int b = blockIdx.x >> 2;
    const size_t bh = (size_t)b * HH + h;

    const int t    = threadIdx.x;
    const int wv   = t >> 6;
    const int lane = t & 63;

    // ---- stage fsl (coalesced) + fdt (transposed) + attn coefs ----
    {
        const float4* s4 = (const float4*)(fs + bh * (FF * OW));
        #pragma unroll
        for (int p = 0; p < 4; ++p) {
            int idx = p * 512 + t;            // 2048 f4
            int i = idx >> 5, kq = idx & 31;
            *(float4*)&fsl[i * 132 + kq * 4] = s4[idx];
        }
        const float* fdg = fd + bh * (FF * OW);
        #pragma unroll
        for (int p = 0; p < 4; ++p) {
            int dq = p * 8 + wv;              // 0..31, wave-uniform
            float4 v = *(const float4*)(fdg + (size_t)lane * OW + dq * 4);
            fdt[(dq * 4 + 0) * 68 + lane] = v.x;
            fdt[(dq * 4 + 1) * 68 + lane] = v.y;
            fdt[(dq * 4 + 2) * 68 + lane] = v.z;
            fdt[(dq * 4 + 3) * 68 + lane] = v.w;
        }
        if (t < 128) {
            float a = attn[h * OW + t];
            A6[t] = 0.6f * a;
            B4[t] = 0.4f * a;
        }
    }
    __syncthreads();

    // ---- cs_i (wave 0), cd_j (wave 1) ----
    if (wv == 0) {
        float s = 0.0f;
        #pragma unroll 8
        for (int c = 0; c < 32; ++c) {
            float4 fv = *(const float4*)&fsl[lane * 132 + c * 4];
            float4 av = *(const float4*)&A6[c * 4];
            s = fmaf(fv.x, av.x, fmaf(fv.y, av.y, fmaf(fv.z, av.z, fmaf(fv.w, av.w, s))));
        }
        cs[lane] = s;
    } else if (wv == 1) {
        float s = 0.0f;
        #pragma unroll 16
        for (int d = 0; d < OW; ++d)
            s = fmaf(fdt[d * 68 + lane], A6[d], s);
        cd[lane] = s;
    }
    __syncthreads();

    // ---- init St[i][j] = cs_i + cd_j ----
    {
        const int i = t >> 3, jb = (t & 7) * 8;
        const float ci = cs[i];
        float4 c0 = *(const float4*)&cd[jb];
        float4 c1 = *(const float4*)&cd[jb + 4];
        float4 o0 = {ci + c0.x, ci + c0.y, ci + c0.z, ci + c0.w};
        float4 o1 = {ci + c1.x, ci + c1.y, ci + c1.z, ci + c1.w};
        *(float4*)&St[i * 68 + jb]     = o0;
        *(float4*)&St[i * 68 + jb + 4] = o1;
    }
    __syncthreads();

    // ---- phase 1: |s| partials, fd in registers, ds_add_f32 combine ----
    {
        const int ie = t >> 7;            // 0..3  -> i0 = ie*16
        const int dh = (t >> 5) & 3;      // 0..3  -> d0 = dh*32
        const int jp = t & 31;            // j0 = jp*2
        const int i0 = ie * 16, d0 = dh * 32, j0 = jp * 2;

        float4 b4r[8];
        #pragma unroll
        for (int q = 0; q < 8; ++q) b4r[q] = *(const float4*)&B4[d0 + q * 4];
        float2 fdr[32];
        #pragma unroll
        for (int dd = 0; dd < 32; ++dd)
            fdr[dd] = *(const float2*)&fdt[(d0 + dd) * 68 + j0];

        float sc0[16], sc1[16];
        #pragma unroll 4
        for (int ii = 0; ii < 16; ++ii) {
            const float* fr = &fsl[(i0 + ii) * 132 + d0];
            float a0 = 0.0f, a1 = 0.0f;
            #pragma unroll
            for (int q = 0; q < 8; ++q) {
                float4 fsv = *(const float4*)(fr + q * 4);
                const float* fe = (const float*)&fsv;
                const float* be = (const float*)&b4r[q];
                #pragma unroll
                for (int e = 0; e < 4; ++e) {
                    const float fv = fe[e];
                    a0 = fmaf(be[e], fabsf(fv + fdr[q * 4 + e].x), a0);
                    a1 = fmaf(be[e], fabsf(fv + fdr[q * 4 + e].y), a1);
                }
            }
            sc0[ii] = a0; sc1[ii] = a1;
        }
        #pragma unroll
        for (int ii = 0; ii < 16; ++ii) {
            atomicAdd(&St[(i0 + ii) * 68 + j0],     sc0[ii]);
            atomicAdd(&St[(i0 + ii) * 68 + j0 + 1], sc1[ii]);
        }
    }
    __syncthreads();

    // ---- phase 2: softmax over i per column j (8 strips of 8 i) ----
    {
        const int j = t & 63, st = t >> 6;
        const int i0 = st * 8;
        float m = St[i0 * 68 + j];
        #pragma unroll
        for (int k = 1; k < 8; ++k) m = fmaxf(m, St[(i0 + k) * 68 + j]);
        redm[st][j] = m;
    }
    __syncthreads();
    {
        const int j = t & 63, st = t >> 6;
        const int i0 = st * 8;
        float mj = redm[0][j];
        #pragma unroll
        for (int s2 = 1; s2 < 8; ++s2) mj = fmaxf(mj, redm[s2][j]);
        float ps = 0.0f;
        #pragma unroll
        for (int k = 0; k < 8; ++k) {
            float e = __expf(St[(i0 + k) * 68 + j] - mj);
            St[(i0 + k) * 68 + j] = e;
            ps += e;
        }
        reds[st][j] = ps;
    }
    __syncthreads();
    if (t < 64) {
        float l = 0.0f;
        #pragma unroll
        for (int s2 = 0; s2 < 8; ++s2) l += reds[s2][t];
        invl[t] = 0.25f / l;                 // head-mean folded
    }
    __syncthreads();

    // ---- phase 3: aggregation 4j x 4d; atomicAdd into out[b][d][j] ----
    {
        const int jg = t & 15, dg = t >> 4;
        const int j0 = jg * 4, d0 = dg * 4;
        float ag[4][4] = {};
        #pragma unroll 4
        for (int i = 0; i < FF; ++i) {
            float4 pv = *(const float4*)&St[i * 68 + j0];
            float4 fv = *(const float4*)&fsl[i * 132 + d0];
            const float* pf = (const float*)&pv;
            const float* fe = (const float*)&fv;
            #pragma unroll
            for (int n = 0; n < 4; ++n) {
                #pragma unroll
                for (int e = 0; e < 4; ++e)
                    ag[n][e] = fmaf(pf[n], fe[e], ag[n][e]);
            }
        }
        float* ob = out + (size_t)b * (OW * FF);
        #pragma unroll
        for (int n = 0; n < 4; ++n) {
            const float iv = invl[j0 + n];
            #pragma unroll
            for (int e = 0; e < 4; ++e)
                atomicAdd(&ob[(size_t)(d0 + e) * FF + j0 + n], ag[n][e] * iv);
        }
    }
}

// ---------------------------------------------------------------------------
extern "C" void kernel_launch(void* const* d_in, const int* in_sizes, int n_in,
                              void* d_out, int out_size, void* d_ws, size_t ws_size,
                              hipStream_t stream) {
    const float* x    = (const float*)d_in[0];
    const float* Wsrc = (const float*)d_in[1];
    const float* bsrc = (const float*)d_in[2];
    const float* Wdst = (const float*)d_in[3];
    const float* bdst = (const float*)d_in[4];
    const float* attn = (const float*)d_in[5];
    float* out = (float*)d_out;

    const size_t SL = (size_t)BB * HH * FF * OW;      // 2M floats = 8 MB
    float* fs = (float*)d_ws;
    float* fd = fs + SL;

    hipMemsetAsync(out, 0, (size_t)out_size * sizeof(float), stream);
    gat_proj<<<BB * 16, 256, 0, stream>>>(x, Wsrc, bsrc, Wdst, bdst, fs, fd);
    gat_attn<<<BB * HH, 512, 0, stream>>>(fs, fd, attn, out);
}